// Round 3
// baseline (2304.270 us; speedup 1.0000x reference)
//
#include <hip/hip_runtime.h>

#define N_NODES 10000
#define N_EDGES 160000

typedef unsigned short u16;
typedef unsigned int   u32;
typedef __bf16 bf16x8 __attribute__((ext_vector_type(8)));
typedef float  f32x4  __attribute__((ext_vector_type(4)));
typedef unsigned short u16x4 __attribute__((ext_vector_type(4)));

struct InP { const void* p[22]; };

// ---------------- workspace layout ----------------
static constexpr size_t WS_FLAG = 0;
static constexpr size_t WS_WIN  = 256;                    // f32 [64][16]
static constexpr size_t WS_WQ   = WS_WIN  + 4096;         // f32 [16][8]
static constexpr size_t WS_WD   = WS_WQ   + 512;          // f32 [8][8]
static constexpr size_t WS_WOUT = WS_WD   + 256;          // f32 [16][64]
static constexpr size_t WS_BK1  = WS_WOUT + 4096;         // f32 128
static constexpr size_t WS_BK2  = WS_BK1  + 512;
static constexpr size_t WS_BK3  = WS_BK2  + 512;          // f32 512
static constexpr size_t WS_BV1  = WS_BK3  + 2048;
static constexpr size_t WS_BV2  = WS_BV1  + 512;
static constexpr size_t WS_BV3  = WS_BV2  + 512;          // f32 1024
static constexpr size_t WS_BNW  = WS_BV3  + 4096;         // f32 64
static constexpr size_t WS_BNB  = WS_BNW  + 256;
// weights fragment-packed bf16 (see k_convert)
static constexpr size_t WS_WK1T = WS_BNB  + 256;          // bf16 4096
static constexpr size_t WS_WK2T = WS_WK1T + 8192;         // bf16 16384
static constexpr size_t WS_WK3T = WS_WK2T + 32768;        // bf16 65536
static constexpr size_t WS_WV1T = WS_WK3T + 131072;       // bf16 4096
static constexpr size_t WS_WV2T = WS_WV1T + 8192;         // bf16 16384
static constexpr size_t WS_WV3T = WS_WV2T + 32768;        // bf16 131072
static constexpr size_t WS_T    = WS_WV3T + 262144;       // f32 [N][16]
static constexpr size_t WS_Q    = WS_T    + (size_t)N_NODES*16*4;  // f32 [N][8]
static constexpr size_t WS_Z    = WS_Q    + (size_t)N_NODES*8*4;   // f32 [N]
static constexpr size_t WS_AGG  = WS_Z    + (size_t)N_NODES*4;     // f32 [N][16]
static constexpr size_t WS_BNS  = WS_AGG  + (size_t)N_NODES*16*4;  // f32 64
static constexpr size_t WS_BNQ  = WS_BNS  + 256;
static constexpr size_t WS_OUTP = WS_BNQ  + 256;          // f32 [N][64]
static constexpr size_t ZERO_OFF = WS_Z;
static constexpr size_t ZERO_LEN = WS_OUTP - WS_Z;

// ---------------- helpers ----------------
__device__ __forceinline__ float loadf(const void* p, long i, int isbf){
  if(isbf){
    u32 x = ((u32)((const u16*)p)[i]) << 16;
    return __uint_as_float(x);
  }
  return ((const float*)p)[i];
}
__device__ __forceinline__ u16 f2b(float f){
  u32 u = __float_as_uint(f);
  u += 0x7fffu + ((u >> 16) & 1u);
  return (u16)(u >> 16);
}
__device__ __forceinline__ float b2f(u16 v){
  return __uint_as_float(((u32)v) << 16);
}
__device__ __forceinline__ bf16x8 ld8(const u16* p){
  uint4 v = *(const uint4*)p;
  return __builtin_bit_cast(bf16x8, v);
}

// ---------------- kernels ----------------
__global__ void k_detect(const void* edge_data, int* flag){
  int lane = threadIdx.x;
  u16 v = ((const u16*)edge_data)[lane*2];
  int ex = (v >> 7) & 0xFF;
  int sane = (ex >= 100 && ex <= 140) ? 1 : 0;
  unsigned long long b = __ballot(sane);
  if(lane == 0) flag[0] = (__popcll(b) >= 48) ? 1 : 0;
}

// weights: fragment-packed. phys index p within a layer (K,N):
//   i=p&7; lane=(p>>3)&63; r2=p>>9; kk=r2%nk; r3=r2/nk; nt=r3&1; c=r3>>1;
//   n = c*32 + nt*16 + (lane&15); k = kk*32 + (lane>>4)*8 + i;  src = W[k][n]
__global__ void k_convert(InP in, char* ws){
  const int isbf = *(const int*)(ws + WS_FLAG);
  long idx = (long)blockIdx.x*256 + threadIdx.x;
  const int    fsrc[12] = {4,5,6,7,9,11,13,15,17,19,20,21};
  const int    fcnt[12] = {1024,128,64,1024,128,128,512,128,128,1024,64,64};
  const size_t fdst[12] = {WS_WIN,WS_WQ,WS_WD,WS_WOUT,WS_BK1,WS_BK2,WS_BK3,WS_BV1,WS_BV2,WS_BV3,WS_BNW,WS_BNB};
  const long F_TOTAL = 4416;
  if(idx < F_TOTAL){
    long g = idx;
    for(int s=0;s<12;s++){
      if(g < fcnt[s]){ ((float*)(ws+fdst[s]))[g] = loadf(in.p[fsrc[s]], g, isbf); return; }
      g -= fcnt[s];
    }
    return;
  }
  long g = idx - F_TOTAL;
  const int    tsrc[6] = {8,10,12,14,16,18};
  const int    tK[6]   = {32,128,128,32,128,128};
  const int    tN[6]   = {128,128,512,128,128,1024};
  const size_t tdst[6] = {WS_WK1T,WS_WK2T,WS_WK3T,WS_WV1T,WS_WV2T,WS_WV3T};
  for(int s=0;s<6;s++){
    long cnt = (long)tK[s]*tN[s];
    if(g < cnt){
      int nk = tK[s] >> 5;
      int i = (int)(g & 7), ln = (int)((g>>3) & 63);
      int r2 = (int)(g >> 9);
      int kk = r2 % nk; int r3 = r2 / nk;
      int nt = r3 & 1;  int c  = r3 >> 1;
      int n = c*32 + nt*16 + (ln & 15);
      int k = kk*32 + (ln >> 4)*8 + i;
      ((u16*)(ws+tdst[s]))[g] = f2b(loadf(in.p[tsrc[s]], (long)k*tN[s] + n, isbf));
      return;
    }
    g -= cnt;
  }
}

__global__ void k_tq(InP in, char* ws){
  const int isbf = *(const int*)(ws + WS_FLAG);
  __shared__ float sWin[1024];
  __shared__ float sWq[128];
  __shared__ float sN[1024];
  __shared__ float sT[256];
  float* t_ws = (float*)(ws+WS_T);
  float* q_ws = (float*)(ws+WS_Q);
  int tid = threadIdx.x;
  for(int i=tid;i<1024;i+=256) sWin[i] = ((const float*)(ws+WS_WIN))[i];
  if(tid<128) sWq[tid] = ((const float*)(ws+WS_WQ))[tid];
  int n0 = blockIdx.x*16;
  for(int i=tid;i<1024;i+=256) sN[i] = loadf(in.p[0], (long)n0*64 + i, isbf);
  __syncthreads();
  int ni = tid>>4, j = tid&15;
  float acc = 0.f;
  #pragma unroll 8
  for(int i=0;i<64;i++) acc += sN[ni*64+i]*sWin[i*16+j];
  float t = acc*0.125f;
  t_ws[(n0+ni)*16+j] = t;
  sT[tid] = t;
  __syncthreads();
  if(tid<128){
    int n2 = tid>>3, b = tid&7;
    float a2 = 0.f;
    #pragma unroll
    for(int jj=0;jj<16;jj++) a2 += sT[n2*16+jj]*sWq[jj*8+b];
    q_ws[(n0+n2)*8+b] = a2*0.25f;
  }
}

// k_edges v4: algorithm of v2/v3 (sH2 eliminated; layer-2 outputs in
// registers; layer-3 per-wave K-slice). Codegen rules learned r1/r2:
//  - every loop indexing af[]/kp[] is #pragma unroll (rule #20: rolled loop
//    -> runtime index -> arrays homed in scratch -> 6.4 GB TCC traffic, the
//    r2 failure)
//  - matvec j loop capped at unroll 2 (full NC unroll -> live-range
//    explosion -> spill, the r1 failure)
__global__ __launch_bounds__(256,3) void k_edges(InP in, char* ws){
  const int isbf = *(const int*)(ws + WS_FLAG);
  const int* ei = (const int*)in.p[1];
  const float* t_ws = (const float*)(ws + WS_T);
  const float* q_ws = (const float*)(ws + WS_Q);
  float* Zp  = (float*)(ws + WS_Z);
  float* AGG = (float*)(ws + WS_AGG);

  // fragment-packed LDS: element (e,k) at tile(e>>4)*stride + (k>>5)*512 + lane(e,k)*8 + (k&7)
  __shared__ __align__(16) char smem[34816];
  u16*   sED = (u16*)smem;               // 4096 B  [4 tiles][512]; tail overlay: sP/sDst
  u16*   sH1 = (u16*)(smem + 4096);      // 16384 B
  u16*   sPT = (u16*)(smem + 20480);     // 8192 B  bf16 [as=64][e=64]
  float* sK  = (float*)(smem + 28672);   // 2048 B  [64][8]; staging alias: sh f32[64][4] (first 1 KB)
  float* sV  = (float*)(smem + 30720);   // 4096 B  [64][16]; staging alias: ts f32[64][16]
  float* sP  = (float*)smem;             // overlay on sED after it's dead
  int*   sDst= (int*)(smem + 256);

  const int tid  = threadIdx.x;
  const int e0   = blockIdx.x * 64;
  const int lane = tid & 63, wv = tid >> 6;
  const int lrow = lane & 15, lquad = lane >> 4;
  const f32x4 z4 = {0.f,0.f,0.f,0.f};

  // ---- staging ----
  {
    int e = tid >> 2, q4 = tid & 3;
    u16 tmp[8];
    if(isbf){
      uint4 vv = *(const uint4*)((const u16*)in.p[2] + (long)(e0+e)*32 + q4*8);
      *(uint4*)tmp = vv;
    } else {
      const float* fp = (const float*)in.p[2] + (long)(e0+e)*32 + q4*8;
      f32x4 a = *(const f32x4*)fp, b = *(const f32x4*)(fp+4);
      #pragma unroll
      for(int r=0;r<4;r++){ tmp[r]=f2b(a[r]); tmp[4+r]=f2b(b[r]); }
    }
    *(uint4*)&sED[(e>>4)*512 + (q4*16 + (e&15))*8] = *(uint4*)tmp;
  }
  {
    int e = tid >> 2, j4 = tid & 3;
    int src = ei[e0+e];
    *(f32x4*)&sV[e*16 + j4*4] = *(const f32x4*)&t_ws[src*16 + j4*4];
  }
  {
    int e = tid >> 2, s4 = tid & 3;
    sK[tid] = loadf(in.p[3], (long)(e0+e)*4 + s4, isbf);
  }
  // wave-0 prefetches q[dst] into registers (used only at the tail)
  float qreg[8]; int mydst = 0;
  if(wv == 0){
    mydst = ei[N_EDGES + e0 + lane];
    #pragma unroll
    for(int a=0;a<8;a++) qreg[a] = q_ws[mydst*8 + a];
  }
  __syncthreads();
  for(int idx = tid; idx < 4096; idx += 256){
    int e = idx & 63, as = idx >> 6;
    sPT[as*64 + e] = f2b(sV[e*16 + (as>>2)] * sK[e*4 + (as&3)]);
  }
  __syncthreads();
  for(int idx = tid; idx < 1536; idx += 256) sK[idx] = 0.f;  // zero sK+sV (contiguous)

  // layer 1: sED -> sH1 (LDS; cross-wave K dependency in layer 2 requires it)
  auto dense1 = [&](const u16* Wg, const float* biasg){
    bf16x8 bw[2]; f32x4 bb[2];
    #pragma unroll
    for(int nt=0;nt<2;nt++){
      bw[nt] = ld8(&Wg[((wv*2+nt)<<9) + lane*8]);
      bb[nt] = *(const f32x4*)&biasg[wv*32 + nt*16 + lquad*4];
    }
    #pragma unroll
    for(int et=0;et<4;et++){
      bf16x8 a = ld8(&sED[et*512 + lane*8]);
      #pragma unroll
      for(int nt=0;nt<2;nt++){
        f32x4 c = __builtin_amdgcn_mfma_f32_16x16x32_bf16(bw[nt], a, bb[nt], 0, 0, 0);
        u16x4 pk;
        #pragma unroll
        for(int r=0;r<4;r++){
          float h = c[r] > 0.f ? c[r] : 0.f;
          pk[r] = f2b(h);
        }
        int off = et*2048 + (wv<<9) + (nt*2 + (lquad>>1))*128 + lrow*8 + (lquad&1)*4;
        *(u16x4*)&sH1[off] = pk;
      }
    }
  };

  // layer 2: sH1 -> registers. Wave wv computes H2 columns [wv*32, wv*32+32),
  // then converts C-fragments to MFMA A-fragments via in-wave shuffles:
  //   reader lane (q=lane>>4, e=lane&15), element i needs H2[e][wv*32 + q*8 + i]
  //   = writer lane ((q&1)*2 + (i>>2))*16 + e, reg c[nt=q>>1][r=i&3].
  bf16x8 af[4];
  auto dense2reg = [&](const u16* Wg, const float* biasg){
    bf16x8 bw[2][4]; f32x4 bb[2];
    #pragma unroll
    for(int nt=0;nt<2;nt++){
      #pragma unroll
      for(int kk=0;kk<4;kk++)
        bw[nt][kk] = ld8(&Wg[(((wv*2+nt)*4 + kk)<<9) + lane*8]);
      bb[nt] = *(const f32x4*)&biasg[wv*32 + nt*16 + lquad*4];
    }
    const int hi = lane >> 5;                       // nt select = q>>1
    const int s0 = ((lane>>4)&1)*32 + (lane&15);    // source lane, low half
    #pragma unroll
    for(int et=0;et<4;et++){
      bf16x8 a0 = ld8(&sH1[et*2048 + (0<<9) + lane*8]);
      bf16x8 a1 = ld8(&sH1[et*2048 + (1<<9) + lane*8]);
      bf16x8 a2 = ld8(&sH1[et*2048 + (2<<9) + lane*8]);
      bf16x8 a3 = ld8(&sH1[et*2048 + (3<<9) + lane*8]);
      u32 p[2][2];
      #pragma unroll
      for(int nt=0;nt<2;nt++){
        f32x4 c = bb[nt];
        c = __builtin_amdgcn_mfma_f32_16x16x32_bf16(bw[nt][0], a0, c, 0, 0, 0);
        c = __builtin_amdgcn_mfma_f32_16x16x32_bf16(bw[nt][1], a1, c, 0, 0, 0);
        c = __builtin_amdgcn_mfma_f32_16x16x32_bf16(bw[nt][2], a2, c, 0, 0, 0);
        c = __builtin_amdgcn_mfma_f32_16x16x32_bf16(bw[nt][3], a3, c, 0, 0, 0);
        float h0 = c[0]>0.f?c[0]:0.f, h1 = c[1]>0.f?c[1]:0.f;
        float h2 = c[2]>0.f?c[2]:0.f, h3 = c[3]>0.f?c[3]:0.f;
        p[nt][0] = ((u32)f2b(h1)<<16) | (u32)f2b(h0);
        p[nt][1] = ((u32)f2b(h3)<<16) | (u32)f2b(h2);
      }
      int a00 = __shfl((int)p[0][0], s0),    a01 = __shfl((int)p[0][1], s0);
      int a10 = __shfl((int)p[1][0], s0),    a11 = __shfl((int)p[1][1], s0);
      int b00 = __shfl((int)p[0][0], s0+16), b01 = __shfl((int)p[0][1], s0+16);
      int b10 = __shfl((int)p[1][0], s0+16), b11 = __shfl((int)p[1][1], s0+16);
      uint4 uv;
      uv.x = (u32)(hi ? a10 : a00);
      uv.y = (u32)(hi ? a11 : a01);
      uv.z = (u32)(hi ? b10 : b00);
      uv.w = (u32)(hi ? b11 : b01);
      af[et] = __builtin_bit_cast(bf16x8, uv);
    }
  };

  // layer 3 + contraction: wave contracts its own K=32 slice (af) against ALL
  // NC n-chunks of 32 cols; bias counted once (wave 0 only); partials combined
  // via sK/sV atomics. j loop: unroll 2 exactly (static cur/nxt, no
  // live-range explosion); et/nt loops fully unrolled (af/kp in registers).
  auto matvec = [&](const u16* Wg, const float* biasg, int NC, int isval){
    float kp[16];
    #pragma unroll
    for(int i=0;i<16;i++) kp[i]=0.f;
    bf16x8 bw[2][2]; f32x4 bb[2][2];
    bb[0][0]=z4; bb[0][1]=z4; bb[1][0]=z4; bb[1][1]=z4;
    #pragma unroll
    for(int nt=0;nt<2;nt++)
      bw[0][nt] = ld8(&Wg[((nt*4 + wv)<<9) + lane*8]);
    if(wv==0){
      bb[0][0] = *(const f32x4*)&biasg[lquad*4];
      bb[0][1] = *(const f32x4*)&biasg[16 + lquad*4];
    }
    #pragma unroll 2
    for(int j=0;j<NC;j++){
      int cur = j&1, nxt = cur^1;
      if(j+1 < NC){
        #pragma unroll
        for(int nt=0;nt<2;nt++)
          bw[nxt][nt] = ld8(&Wg[((((j+1)*2+nt)*4 + wv)<<9) + lane*8]);
        if(wv==0){
          bb[nxt][0] = *(const f32x4*)&biasg[(j+1)*32 + lquad*4];
          bb[nxt][1] = *(const f32x4*)&biasg[(j+1)*32 + 16 + lquad*4];
        }
      }
      #pragma unroll
      for(int et=0;et<4;et++){
        const int e = et*16 + lrow;
        #pragma unroll
        for(int nt=0;nt<2;nt++){
          f32x4 c = __builtin_amdgcn_mfma_f32_16x16x32_bf16(bw[cur][nt], af[et], bb[cur][nt], 0, 0, 0);
          int n0 = j*32 + nt*16 + lquad*4;
          int as = isval ? (n0>>4) : (n0>>3);
          float pv = b2f(sPT[as*64 + e]);
          #pragma unroll
          for(int r=0;r<4;r++)
            kp[et*4+r] += pv * c[r];
        }
      }
    }
    if(isval){
      #pragma unroll
      for(int et=0;et<4;et++){
        int e = et*16 + lrow;
        #pragma unroll
        for(int r=0;r<4;r++)
          atomicAdd(&sV[e*16 + lquad*4 + r], kp[et*4+r]*0.125f);
      }
    } else {
      int b0 = (lquad & 1)*4;
      #pragma unroll
      for(int et=0;et<4;et++){
        int e = et*16 + lrow;
        #pragma unroll
        for(int r=0;r<4;r++)
          atomicAdd(&sK[e*8 + b0 + r], kp[et*4+r]*0.125f);
      }
    }
  };

  dense1((const u16*)(ws+WS_WK1T), (const float*)(ws+WS_BK1));
  __syncthreads();                                   // sH1 ready (+ sK/sV zeroed)
  dense2reg((const u16*)(ws+WS_WK2T), (const float*)(ws+WS_BK2));
  matvec((const u16*)(ws+WS_WK3T), (const float*)(ws+WS_BK3), 16, 0);
  __syncthreads();                                   // all sH1 reads done; sK complete
  dense1((const u16*)(ws+WS_WV1T), (const float*)(ws+WS_BV1));
  __syncthreads();                                   // sH1 ready
  dense2reg((const u16*)(ws+WS_WV2T), (const float*)(ws+WS_BV2));
  matvec((const u16*)(ws+WS_WV3T), (const float*)(ws+WS_BV3), 32, 1);
  __syncthreads();                                   // sV complete

  // ---- tail: logit, exp, z; then p*v -> AGG ----
  if(wv == 0){
    const float* wdf = (const float*)(ws + WS_WD);
    float acc = 0.f;
    #pragma unroll
    for(int a=0;a<8;a++){
      float qa = qreg[a];
      #pragma unroll
      for(int b=0;b<8;b++)
        acc += qa * wdf[a*8+b] * sK[lane*8+b];
    }
    float p = __expf(acc * 0.125f);
    atomicAdd(Zp + mydst, p);
    sP[lane] = p;
    sDst[lane] = mydst;
  }
  __syncthreads();
  for(int idx = tid; idx < 1024; idx += 256){
    int e = idx >> 4;
    atomicAdd(AGG + (long)sDst[e]*16 + (idx & 15), sP[e]*sV[idx]);
  }
}

__global__ void k7a(InP in, char* ws){
  const int isbf = *(const int*)(ws + WS_FLAG);
  __shared__ float sWo[1024];
  __shared__ float ls[256], lq[256];
  int tid = threadIdx.x;
  for(int i=tid;i<1024;i+=256) sWo[i] = ((const float*)(ws+WS_WOUT))[i];
  __syncthreads();
  const float* AGG = (const float*)(ws+WS_AGG);
  const float* Zp  = (const float*)(ws+WS_Z);
  float* OUTP = (float*)(ws+WS_OUTP);
  int c = tid & 63, r4 = tid >> 6;
  float s=0.f, q=0.f;
  for(int it=0; it<20; it++){
    int n = blockIdx.x*80 + it*4 + r4;
    float z = Zp[n];
    float inv = z > 0.f ? 0.25f/z : 0.f;
    const float* ag = AGG + (long)n*16;
    float acc = 0.f;
    #pragma unroll
    for(int j=0;j<16;j++) acc += ag[j]*sWo[j*64+c];
    float o = acc*inv + loadf(in.p[0], (long)n*64 + c, isbf);
    OUTP[(long)n*64+c] = o;
    s += o; q += o*o;
  }
  ls[tid]=s; lq[tid]=q;
  __syncthreads();
  if(tid < 64){
    float ss = ls[tid]+ls[tid+64]+ls[tid+128]+ls[tid+192];
    float qq = lq[tid]+lq[tid+64]+lq[tid+128]+lq[tid+192];
    atomicAdd((float*)(ws+WS_BNS)+tid, ss);
    atomicAdd((float*)(ws+WS_BNQ)+tid, qq);
  }
}

__global__ void k7c(char* ws, void* d_out){
  const int isbf = *(const int*)(ws + WS_FLAG);
  int idx = blockIdx.x*256 + threadIdx.x;
  if(idx >= N_NODES*64) return;
  int c = idx & 63;
  float s  = ((const float*)(ws+WS_BNS))[c];
  float qq = ((const float*)(ws+WS_BNQ))[c];
  float mean = s * (1.f/N_NODES);
  float var  = qq * (1.f/N_NODES) - mean*mean;
  float sc = rsqrtf(var + 1e-5f) * ((const float*)(ws+WS_BNW))[c];
  float val = (((const float*)(ws+WS_OUTP))[idx] - mean)*sc + ((const float*)(ws+WS_BNB))[c];
  if(isbf) ((u16*)d_out)[idx] = f2b(val);
  else     ((float*)d_out)[idx] = val;
}

extern "C" void kernel_launch(void* const* d_in, const int* in_sizes, int n_in,
                              void* d_out, int out_size, void* d_ws, size_t ws_size,
                              hipStream_t stream){
  InP in;
  for(int i=0;i<22;i++) in.p[i] = d_in[i];
  char* ws = (char*)d_ws;

  hipMemsetAsync(ws + ZERO_OFF, 0, ZERO_LEN, stream);
  k_detect<<<1,64,0,stream>>>((const void*)d_in[2], (int*)(ws+WS_FLAG));
  k_convert<<<946,256,0,stream>>>(in, ws);
  k_tq<<<625,256,0,stream>>>(in, ws);
  k_edges<<<2500,256,0,stream>>>(in, ws);
  k7a<<<125,256,0,stream>>>(in, ws);
  k7c<<<2500,256,0,stream>>>(ws, d_out);
}

// Round 4
// 328.062 us; speedup vs baseline: 7.0239x; 7.0239x over previous
//
#include <hip/hip_runtime.h>

#define N_NODES 10000
#define N_EDGES 160000

typedef unsigned short u16;
typedef unsigned int   u32;
typedef __bf16 bf16x8 __attribute__((ext_vector_type(8)));
typedef float  f32x4  __attribute__((ext_vector_type(4)));
typedef unsigned short u16x4 __attribute__((ext_vector_type(4)));

struct InP { const void* p[22]; };

// ---------------- workspace layout ----------------
static constexpr size_t WS_FLAG = 0;
static constexpr size_t WS_WIN  = 256;                    // f32 [64][16]
static constexpr size_t WS_WQ   = WS_WIN  + 4096;         // f32 [16][8]
static constexpr size_t WS_WD   = WS_WQ   + 512;          // f32 [8][8]
static constexpr size_t WS_WOUT = WS_WD   + 256;          // f32 [16][64]
static constexpr size_t WS_BK1  = WS_WOUT + 4096;         // f32 128
static constexpr size_t WS_BK2  = WS_BK1  + 512;
static constexpr size_t WS_BK3  = WS_BK2  + 512;          // f32 512
static constexpr size_t WS_BV1  = WS_BK3  + 2048;
static constexpr size_t WS_BV2  = WS_BV1  + 512;
static constexpr size_t WS_BV3  = WS_BV2  + 512;          // f32 1024
static constexpr size_t WS_BNW  = WS_BV3  + 4096;         // f32 64
static constexpr size_t WS_BNB  = WS_BNW  + 256;
// weights fragment-packed bf16 (see k_convert)
static constexpr size_t WS_WK1T = WS_BNB  + 256;          // bf16 4096
static constexpr size_t WS_WK2T = WS_WK1T + 8192;         // bf16 16384
static constexpr size_t WS_WK3T = WS_WK2T + 32768;        // bf16 65536
static constexpr size_t WS_WV1T = WS_WK3T + 131072;       // bf16 4096
static constexpr size_t WS_WV2T = WS_WV1T + 8192;         // bf16 16384
static constexpr size_t WS_WV3T = WS_WV2T + 32768;        // bf16 131072
static constexpr size_t WS_T    = WS_WV3T + 262144;       // f32 [N][16]
static constexpr size_t WS_Q    = WS_T    + (size_t)N_NODES*16*4;  // f32 [N][8]
static constexpr size_t WS_Z    = WS_Q    + (size_t)N_NODES*8*4;   // f32 [N]
static constexpr size_t WS_AGG  = WS_Z    + (size_t)N_NODES*4;     // f32 [N][16]
static constexpr size_t WS_BNS  = WS_AGG  + (size_t)N_NODES*16*4;  // f32 64
static constexpr size_t WS_BNQ  = WS_BNS  + 256;
static constexpr size_t WS_OUTP = WS_BNQ  + 256;          // f32 [N][64]
static constexpr size_t ZERO_OFF = WS_Z;
static constexpr size_t ZERO_LEN = WS_OUTP - WS_Z;

// ---------------- helpers ----------------
__device__ __forceinline__ float loadf(const void* p, long i, int isbf){
  if(isbf){
    u32 x = ((u32)((const u16*)p)[i]) << 16;
    return __uint_as_float(x);
  }
  return ((const float*)p)[i];
}
__device__ __forceinline__ u16 f2b(float f){
  u32 u = __float_as_uint(f);
  u += 0x7fffu + ((u >> 16) & 1u);
  return (u16)(u >> 16);
}
__device__ __forceinline__ float b2f(u16 v){
  return __uint_as_float(((u32)v) << 16);
}
__device__ __forceinline__ bf16x8 ld8(const u16* p){
  uint4 v = *(const uint4*)p;
  return __builtin_bit_cast(bf16x8, v);
}

// ---------------- kernels ----------------
__global__ void k_detect(const void* edge_data, int* flag){
  int lane = threadIdx.x;
  u16 v = ((const u16*)edge_data)[lane*2];
  int ex = (v >> 7) & 0xFF;
  int sane = (ex >= 100 && ex <= 140) ? 1 : 0;
  unsigned long long b = __ballot(sane);
  if(lane == 0) flag[0] = (__popcll(b) >= 48) ? 1 : 0;
}

// weights: fragment-packed. phys index p within a layer (K,N):
//   i=p&7; lane=(p>>3)&63; r2=p>>9; kk=r2%nk; r3=r2/nk; nt=r3&1; c=r3>>1;
//   n = c*32 + nt*16 + (lane&15); k = kk*32 + (lane>>4)*8 + i;  src = W[k][n]
__global__ void k_convert(InP in, char* ws){
  const int isbf = *(const int*)(ws + WS_FLAG);
  long idx = (long)blockIdx.x*256 + threadIdx.x;
  const int    fsrc[12] = {4,5,6,7,9,11,13,15,17,19,20,21};
  const int    fcnt[12] = {1024,128,64,1024,128,128,512,128,128,1024,64,64};
  const size_t fdst[12] = {WS_WIN,WS_WQ,WS_WD,WS_WOUT,WS_BK1,WS_BK2,WS_BK3,WS_BV1,WS_BV2,WS_BV3,WS_BNW,WS_BNB};
  const long F_TOTAL = 4416;
  if(idx < F_TOTAL){
    long g = idx;
    for(int s=0;s<12;s++){
      if(g < fcnt[s]){ ((float*)(ws+fdst[s]))[g] = loadf(in.p[fsrc[s]], g, isbf); return; }
      g -= fcnt[s];
    }
    return;
  }
  long g = idx - F_TOTAL;
  const int    tsrc[6] = {8,10,12,14,16,18};
  const int    tK[6]   = {32,128,128,32,128,128};
  const int    tN[6]   = {128,128,512,128,128,1024};
  const size_t tdst[6] = {WS_WK1T,WS_WK2T,WS_WK3T,WS_WV1T,WS_WV2T,WS_WV3T};
  for(int s=0;s<6;s++){
    long cnt = (long)tK[s]*tN[s];
    if(g < cnt){
      int nk = tK[s] >> 5;
      int i = (int)(g & 7), ln = (int)((g>>3) & 63);
      int r2 = (int)(g >> 9);
      int kk = r2 % nk; int r3 = r2 / nk;
      int nt = r3 & 1;  int c  = r3 >> 1;
      int n = c*32 + nt*16 + (ln & 15);
      int k = kk*32 + (ln >> 4)*8 + i;
      ((u16*)(ws+tdst[s]))[g] = f2b(loadf(in.p[tsrc[s]], (long)k*tN[s] + n, isbf));
      return;
    }
    g -= cnt;
  }
}

__global__ void k_tq(InP in, char* ws){
  const int isbf = *(const int*)(ws + WS_FLAG);
  __shared__ float sWin[1024];
  __shared__ float sWq[128];
  __shared__ float sN[1024];
  __shared__ float sT[256];
  float* t_ws = (float*)(ws+WS_T);
  float* q_ws = (float*)(ws+WS_Q);
  int tid = threadIdx.x;
  for(int i=tid;i<1024;i+=256) sWin[i] = ((const float*)(ws+WS_WIN))[i];
  if(tid<128) sWq[tid] = ((const float*)(ws+WS_WQ))[tid];
  int n0 = blockIdx.x*16;
  for(int i=tid;i<1024;i+=256) sN[i] = loadf(in.p[0], (long)n0*64 + i, isbf);
  __syncthreads();
  int ni = tid>>4, j = tid&15;
  float acc = 0.f;
  #pragma unroll 8
  for(int i=0;i<64;i++) acc += sN[ni*64+i]*sWin[i*16+j];
  float t = acc*0.125f;
  t_ws[(n0+ni)*16+j] = t;
  sT[tid] = t;
  __syncthreads();
  if(tid<128){
    int n2 = tid>>3, b = tid&7;
    float a2 = 0.f;
    #pragma unroll
    for(int jj=0;jj<16;jj++) a2 += sT[n2*16+jj]*sWq[jj*8+b];
    q_ws[(n0+n2)*8+b] = a2*0.25f;
  }
}

// ---- k_edges v5 device functions: no lambdas, no by-ref capture, no runtime
// trip counts. Theory from r1-r3 failures: the dense2reg/matvec LAMBDAS were
// outlined (called twice, big bodies, runtime NC); by-reference capture of
// af[] made its address escape -> af/kp homed in scratch -> 6.4 GB TCC
// traffic that also evicted the L2-resident weights. Fused single
// __forceinline__ function + named scalars removes every escape path.

__device__ __forceinline__ void dense1(int wv, int lane, int lquad, int lrow,
                                       const u16* __restrict__ Wg,
                                       const float* __restrict__ biasg,
                                       const u16* sED, u16* sH1){
  bf16x8 bw0 = ld8(&Wg[((wv*2+0)<<9) + lane*8]);
  bf16x8 bw1 = ld8(&Wg[((wv*2+1)<<9) + lane*8]);
  f32x4 bb0 = *(const f32x4*)&biasg[wv*32 +  0 + lquad*4];
  f32x4 bb1 = *(const f32x4*)&biasg[wv*32 + 16 + lquad*4];
  #pragma unroll
  for(int et=0;et<4;et++){
    bf16x8 a = ld8(&sED[et*512 + lane*8]);
    f32x4 c0 = __builtin_amdgcn_mfma_f32_16x16x32_bf16(bw0, a, bb0, 0, 0, 0);
    f32x4 c1 = __builtin_amdgcn_mfma_f32_16x16x32_bf16(bw1, a, bb1, 0, 0, 0);
    u16x4 pk0, pk1;
    #pragma unroll
    for(int r=0;r<4;r++){
      float h0 = c0[r] > 0.f ? c0[r] : 0.f; pk0[r] = f2b(h0);
      float h1 = c1[r] > 0.f ? c1[r] : 0.f; pk1[r] = f2b(h1);
    }
    int base = et*2048 + (wv<<9) + (lquad>>1)*128 + lrow*8 + (lquad&1)*4;
    *(u16x4*)&sH1[base      ] = pk0;   // nt=0
    *(u16x4*)&sH1[base + 256] = pk1;   // nt=1: (nt*2)*128
  }
}

// fused layer2 (sH1 -> af0..af3 registers via MFMA + in-wave shuffle) and
// layer3 (per-wave K=32 slice vs all NC n-chunks, contracted with sPT,
// partials atomically combined into sKV).
template<int NC, int ISVAL>
__device__ __forceinline__ void l23(int wv, int lane, int lquad, int lrow,
                                    const u16* __restrict__ W2, const float* __restrict__ b2,
                                    const u16* __restrict__ W3, const float* __restrict__ b3,
                                    const u16* sH1, const u16* sPT, float* sKV){
  const int hi = lane >> 5;
  const int s0 = ((lane>>4)&1)*32 + (lane&15);

  // layer-2 weights: [nt][kk] as named regs
  bf16x8 w20 = ld8(&W2[(((wv*2+0)*4+0)<<9) + lane*8]);
  bf16x8 w21 = ld8(&W2[(((wv*2+0)*4+1)<<9) + lane*8]);
  bf16x8 w22 = ld8(&W2[(((wv*2+0)*4+2)<<9) + lane*8]);
  bf16x8 w23 = ld8(&W2[(((wv*2+0)*4+3)<<9) + lane*8]);
  bf16x8 w24 = ld8(&W2[(((wv*2+1)*4+0)<<9) + lane*8]);
  bf16x8 w25 = ld8(&W2[(((wv*2+1)*4+1)<<9) + lane*8]);
  bf16x8 w26 = ld8(&W2[(((wv*2+1)*4+2)<<9) + lane*8]);
  bf16x8 w27 = ld8(&W2[(((wv*2+1)*4+3)<<9) + lane*8]);
  f32x4 bb20 = *(const f32x4*)&b2[wv*32 +  0 + lquad*4];
  f32x4 bb21 = *(const f32x4*)&b2[wv*32 + 16 + lquad*4];

  bf16x8 af0, af1, af2, af3;
#define D2_ET(ET, AF) { \
    bf16x8 a0 = ld8(&sH1[ET*2048 + (0<<9) + lane*8]); \
    bf16x8 a1 = ld8(&sH1[ET*2048 + (1<<9) + lane*8]); \
    bf16x8 a2 = ld8(&sH1[ET*2048 + (2<<9) + lane*8]); \
    bf16x8 a3 = ld8(&sH1[ET*2048 + (3<<9) + lane*8]); \
    f32x4 c0 = bb20, c1 = bb21; \
    c0 = __builtin_amdgcn_mfma_f32_16x16x32_bf16(w20, a0, c0, 0, 0, 0); \
    c0 = __builtin_amdgcn_mfma_f32_16x16x32_bf16(w21, a1, c0, 0, 0, 0); \
    c0 = __builtin_amdgcn_mfma_f32_16x16x32_bf16(w22, a2, c0, 0, 0, 0); \
    c0 = __builtin_amdgcn_mfma_f32_16x16x32_bf16(w23, a3, c0, 0, 0, 0); \
    c1 = __builtin_amdgcn_mfma_f32_16x16x32_bf16(w24, a0, c1, 0, 0, 0); \
    c1 = __builtin_amdgcn_mfma_f32_16x16x32_bf16(w25, a1, c1, 0, 0, 0); \
    c1 = __builtin_amdgcn_mfma_f32_16x16x32_bf16(w26, a2, c1, 0, 0, 0); \
    c1 = __builtin_amdgcn_mfma_f32_16x16x32_bf16(w27, a3, c1, 0, 0, 0); \
    float h0 = c0[0]>0.f?c0[0]:0.f, h1 = c0[1]>0.f?c0[1]:0.f; \
    float h2 = c0[2]>0.f?c0[2]:0.f, h3 = c0[3]>0.f?c0[3]:0.f; \
    u32 p00 = ((u32)f2b(h1)<<16) | (u32)f2b(h0); \
    u32 p01 = ((u32)f2b(h3)<<16) | (u32)f2b(h2); \
    h0 = c1[0]>0.f?c1[0]:0.f; h1 = c1[1]>0.f?c1[1]:0.f; \
    h2 = c1[2]>0.f?c1[2]:0.f; h3 = c1[3]>0.f?c1[3]:0.f; \
    u32 p10 = ((u32)f2b(h1)<<16) | (u32)f2b(h0); \
    u32 p11 = ((u32)f2b(h3)<<16) | (u32)f2b(h2); \
    int a00 = __shfl((int)p00, s0),    a01 = __shfl((int)p01, s0); \
    int a10 = __shfl((int)p10, s0),    a11 = __shfl((int)p11, s0); \
    int b00 = __shfl((int)p00, s0+16), b01 = __shfl((int)p01, s0+16); \
    int b10 = __shfl((int)p10, s0+16), b11 = __shfl((int)p11, s0+16); \
    uint4 uv; \
    uv.x = (u32)(hi ? a10 : a00); \
    uv.y = (u32)(hi ? a11 : a01); \
    uv.z = (u32)(hi ? b10 : b00); \
    uv.w = (u32)(hi ? b11 : b01); \
    AF = __builtin_bit_cast(bf16x8, uv); }
  D2_ET(0, af0)
  D2_ET(1, af1)
  D2_ET(2, af2)
  D2_ET(3, af3)
#undef D2_ET

  // layer 3 + contraction
  f32x4 kp0 = {0.f,0.f,0.f,0.f}, kp1 = {0.f,0.f,0.f,0.f};
  f32x4 kp2 = {0.f,0.f,0.f,0.f}, kp3 = {0.f,0.f,0.f,0.f};
#define MV_ET(ET, AF, KP) { \
      const int e = ET*16 + lrow; \
      f32x4 c0 = __builtin_amdgcn_mfma_f32_16x16x32_bf16(w30, AF, bb30, 0, 0, 0); \
      f32x4 c1 = __builtin_amdgcn_mfma_f32_16x16x32_bf16(w31, AF, bb31, 0, 0, 0); \
      const int n00 = j*32 +  0 + lquad*4; \
      const int n01 = j*32 + 16 + lquad*4; \
      const int as0 = ISVAL ? (n00>>4) : (n00>>3); \
      const int as1 = ISVAL ? (n01>>4) : (n01>>3); \
      const float pv0 = b2f(sPT[as0*64 + e]); \
      const float pv1 = b2f(sPT[as1*64 + e]); \
      KP += c0*pv0 + c1*pv1; }
  #pragma unroll 2
  for(int j=0;j<NC;j++){
    bf16x8 w30 = ld8(&W3[(((j*2+0)*4 + wv)<<9) + lane*8]);
    bf16x8 w31 = ld8(&W3[(((j*2+1)*4 + wv)<<9) + lane*8]);
    f32x4 bb30 = {0.f,0.f,0.f,0.f}, bb31 = {0.f,0.f,0.f,0.f};
    if(wv == 0){
      bb30 = *(const f32x4*)&b3[j*32 +  0 + lquad*4];
      bb31 = *(const f32x4*)&b3[j*32 + 16 + lquad*4];
    }
    MV_ET(0, af0, kp0)
    MV_ET(1, af1, kp1)
    MV_ET(2, af2, kp2)
    MV_ET(3, af3, kp3)
  }
#undef MV_ET

  const int b0     = ISVAL ? (lquad*4) : ((lquad&1)*4);
  const int stride = ISVAL ? 16 : 8;
#define ST_ET(ET, KP) { \
    const int e = ET*16 + lrow; \
    atomicAdd(&sKV[e*stride + b0 + 0], KP[0]*0.125f); \
    atomicAdd(&sKV[e*stride + b0 + 1], KP[1]*0.125f); \
    atomicAdd(&sKV[e*stride + b0 + 2], KP[2]*0.125f); \
    atomicAdd(&sKV[e*stride + b0 + 3], KP[3]*0.125f); }
  ST_ET(0, kp0)
  ST_ET(1, kp1)
  ST_ET(2, kp2)
  ST_ET(3, kp3)
#undef ST_ET
}

__global__ __launch_bounds__(256,3) void k_edges(InP in, char* ws){
  const int isbf = *(const int*)(ws + WS_FLAG);
  const int* ei = (const int*)in.p[1];
  const float* t_ws = (const float*)(ws + WS_T);
  const float* q_ws = (const float*)(ws + WS_Q);
  float* Zp  = (float*)(ws + WS_Z);
  float* AGG = (float*)(ws + WS_AGG);

  // fragment-packed LDS: element (e,k) at tile(e>>4)*stride + (k>>5)*512 + lane(e,k)*8 + (k&7)
  __shared__ __align__(16) char smem[34816];
  u16*   sED = (u16*)smem;               // 4096 B  [4 tiles][512]; tail overlay: sP/sDst
  u16*   sH1 = (u16*)(smem + 4096);      // 16384 B
  u16*   sPT = (u16*)(smem + 20480);     // 8192 B  bf16 [as=64][e=64]
  float* sK  = (float*)(smem + 28672);   // 2048 B  [64][8]; staging alias: sh f32[64][4] (first 1 KB)
  float* sV  = (float*)(smem + 30720);   // 4096 B  [64][16]; staging alias: ts f32[64][16]
  float* sP  = (float*)smem;             // overlay on sED after it's dead
  int*   sDst= (int*)(smem + 256);

  const int tid  = threadIdx.x;
  const int e0   = blockIdx.x * 64;
  const int lane = tid & 63, wv = tid >> 6;
  const int lrow = lane & 15, lquad = lane >> 4;

  // ---- staging ----
  {
    int e = tid >> 2, q4 = tid & 3;
    u16 tmp[8];
    if(isbf){
      uint4 vv = *(const uint4*)((const u16*)in.p[2] + (long)(e0+e)*32 + q4*8);
      *(uint4*)tmp = vv;
    } else {
      const float* fp = (const float*)in.p[2] + (long)(e0+e)*32 + q4*8;
      f32x4 a = *(const f32x4*)fp, b = *(const f32x4*)(fp+4);
      #pragma unroll
      for(int r=0;r<4;r++){ tmp[r]=f2b(a[r]); tmp[4+r]=f2b(b[r]); }
    }
    *(uint4*)&sED[(e>>4)*512 + (q4*16 + (e&15))*8] = *(uint4*)tmp;
  }
  {
    int e = tid >> 2, j4 = tid & 3;
    int src = ei[e0+e];
    *(f32x4*)&sV[e*16 + j4*4] = *(const f32x4*)&t_ws[src*16 + j4*4];
  }
  {
    int e = tid >> 2, s4 = tid & 3;
    sK[tid] = loadf(in.p[3], (long)(e0+e)*4 + s4, isbf);
  }
  // wave-0 prefetches q[dst] into registers (used only at the tail)
  float qreg[8]; int mydst = 0;
  if(wv == 0){
    mydst = ei[N_EDGES + e0 + lane];
    #pragma unroll
    for(int a=0;a<8;a++) qreg[a] = q_ws[mydst*8 + a];
  }
  __syncthreads();
  for(int idx = tid; idx < 4096; idx += 256){
    int e = idx & 63, as = idx >> 6;
    sPT[as*64 + e] = f2b(sV[e*16 + (as>>2)] * sK[e*4 + (as&3)]);
  }
  __syncthreads();
  for(int idx = tid; idx < 1536; idx += 256) sK[idx] = 0.f;  // zero sK+sV (contiguous)

  dense1(wv, lane, lquad, lrow, (const u16*)(ws+WS_WK1T), (const float*)(ws+WS_BK1), sED, sH1);
  __syncthreads();                                   // sH1 ready (+ sK/sV zeroed)
  l23<16,0>(wv, lane, lquad, lrow,
            (const u16*)(ws+WS_WK2T), (const float*)(ws+WS_BK2),
            (const u16*)(ws+WS_WK3T), (const float*)(ws+WS_BK3), sH1, sPT, sK);
  __syncthreads();                                   // all sH1 reads done; sK complete
  dense1(wv, lane, lquad, lrow, (const u16*)(ws+WS_WV1T), (const float*)(ws+WS_BV1), sED, sH1);
  __syncthreads();                                   // sH1 ready
  l23<32,1>(wv, lane, lquad, lrow,
            (const u16*)(ws+WS_WV2T), (const float*)(ws+WS_BV2),
            (const u16*)(ws+WS_WV3T), (const float*)(ws+WS_BV3), sH1, sPT, sV);
  __syncthreads();                                   // sV complete

  // ---- tail: logit, exp, z; then p*v -> AGG ----
  if(wv == 0){
    const float* wdf = (const float*)(ws + WS_WD);
    float acc = 0.f;
    #pragma unroll
    for(int a=0;a<8;a++){
      float qa = qreg[a];
      #pragma unroll
      for(int b=0;b<8;b++)
        acc += qa * wdf[a*8+b] * sK[lane*8+b];
    }
    float p = __expf(acc * 0.125f);
    atomicAdd(Zp + mydst, p);
    sP[lane] = p;
    sDst[lane] = mydst;
  }
  __syncthreads();
  for(int idx = tid; idx < 1024; idx += 256){
    int e = idx >> 4;
    atomicAdd(AGG + (long)sDst[e]*16 + (idx & 15), sP[e]*sV[idx]);
  }
}

__global__ void k7a(InP in, char* ws){
  const int isbf = *(const int*)(ws + WS_FLAG);
  __shared__ float sWo[1024];
  __shared__ float ls[256], lq[256];
  int tid = threadIdx.x;
  for(int i=tid;i<1024;i+=256) sWo[i] = ((const float*)(ws+WS_WOUT))[i];
  __syncthreads();
  const float* AGG = (const float*)(ws+WS_AGG);
  const float* Zp  = (const float*)(ws+WS_Z);
  float* OUTP = (float*)(ws+WS_OUTP);
  int c = tid & 63, r4 = tid >> 6;
  float s=0.f, q=0.f;
  for(int it=0; it<20; it++){
    int n = blockIdx.x*80 + it*4 + r4;
    float z = Zp[n];
    float inv = z > 0.f ? 0.25f/z : 0.f;
    const float* ag = AGG + (long)n*16;
    float acc = 0.f;
    #pragma unroll
    for(int j=0;j<16;j++) acc += ag[j]*sWo[j*64+c];
    float o = acc*inv + loadf(in.p[0], (long)n*64 + c, isbf);
    OUTP[(long)n*64+c] = o;
    s += o; q += o*o;
  }
  ls[tid]=s; lq[tid]=q;
  __syncthreads();
  if(tid < 64){
    float ss = ls[tid]+ls[tid+64]+ls[tid+128]+ls[tid+192];
    float qq = lq[tid]+lq[tid+64]+lq[tid+128]+lq[tid+192];
    atomicAdd((float*)(ws+WS_BNS)+tid, ss);
    atomicAdd((float*)(ws+WS_BNQ)+tid, qq);
  }
}

__global__ void k7c(char* ws, void* d_out){
  const int isbf = *(const int*)(ws + WS_FLAG);
  int idx = blockIdx.x*256 + threadIdx.x;
  if(idx >= N_NODES*64) return;
  int c = idx & 63;
  float s  = ((const float*)(ws+WS_BNS))[c];
  float qq = ((const float*)(ws+WS_BNQ))[c];
  float mean = s * (1.f/N_NODES);
  float var  = qq * (1.f/N_NODES) - mean*mean;
  float sc = rsqrtf(var + 1e-5f) * ((const float*)(ws+WS_BNW))[c];
  float val = (((const float*)(ws+WS_OUTP))[idx] - mean)*sc + ((const float*)(ws+WS_BNB))[c];
  if(isbf) ((u16*)d_out)[idx] = f2b(val);
  else     ((float*)d_out)[idx] = val;
}

extern "C" void kernel_launch(void* const* d_in, const int* in_sizes, int n_in,
                              void* d_out, int out_size, void* d_ws, size_t ws_size,
                              hipStream_t stream){
  InP in;
  for(int i=0;i<22;i++) in.p[i] = d_in[i];
  char* ws = (char*)d_ws;

  hipMemsetAsync(ws + ZERO_OFF, 0, ZERO_LEN, stream);
  k_detect<<<1,64,0,stream>>>((const void*)d_in[2], (int*)(ws+WS_FLAG));
  k_convert<<<946,256,0,stream>>>(in, ws);
  k_tq<<<625,256,0,stream>>>(in, ws);
  k_edges<<<2500,256,0,stream>>>(in, ws);
  k7a<<<125,256,0,stream>>>(in, ws);
  k7c<<<2500,256,0,stream>>>(ws, d_out);
}